// Round 1
// baseline (661.928 us; speedup 1.0000x reference)
//
#include <hip/hip_runtime.h>
#include <hip/hip_bf16.h>

#define BATCH 32
#define CIN   256
#define OCH   256
#define HW    56
#define PW    58
#define PAREA (PW*PW)   /* 3364 */
#define PLANE (HW*HW)   /* 3136 */

typedef float float4v __attribute__((ext_vector_type(4)));
typedef short short8  __attribute__((ext_vector_type(8)));

__device__ __forceinline__ unsigned short f2bf(float f) {
  union { float f; unsigned u; } v; v.f = f;
  unsigned r = v.u + 0x7fffu + ((v.u >> 16) & 1u);
  return (unsigned short)(r >> 16);
}

// async global->LDS, 16B per lane, LDS dest must be linear in lane order
__device__ __forceinline__ void gll16(const unsigned short* g, unsigned short* l) {
  __builtin_amdgcn_global_load_lds(
      (const __attribute__((address_space(1))) void*)g,
      (__attribute__((address_space(3))) void*)l,
      16, 0, 0);
}

// ---------------- Kernel 1: adaptive avg+max pool (56x56 -> 5x5) ----------------
__global__ __launch_bounds__(256) void pool_kernel(const float* __restrict__ x,
                                                   float* __restrict__ avgp,
                                                   float* __restrict__ maxp) {
  __shared__ float plane[PLANE];
  int bc = blockIdx.x;  // b*256 + c
  const float* src = x + (size_t)bc * PLANE;
  for (int e = threadIdx.x; e < PLANE; e += 256) plane[e] = src[e];
  __syncthreads();
  if (threadIdx.x < 25) {
    int i = threadIdx.x / 5, j = threadIdx.x % 5;
    int r0 = (i * HW) / 5, r1 = ((i + 1) * HW + 4) / 5;
    int c0 = (j * HW) / 5, c1 = ((j + 1) * HW + 4) / 5;
    float s = 0.f, m = -1e30f;
    for (int r = r0; r < r1; ++r)
      for (int c = c0; c < c1; ++c) {
        float v = plane[r * HW + c];
        s += v; m = fmaxf(m, v);
      }
    avgp[(size_t)bc * 25 + threadIdx.x] = s / (float)((r1 - r0) * (c1 - c0));
    maxp[(size_t)bc * 25 + threadIdx.x] = m;
  }
}

// ---------------- Kernel 2: dynamic weight computation ----------------
// New Wbf layout: [b][ocb2][icb8][r9][oc 128][ic 32], PRE-SWIZZLED:
//   logical ic-chunk c (0..3, 8 bf16 each) stored at chunk c ^ ((ocl>>1)&3)
__global__ __launch_bounds__(256) void wcalc_kernel(
    const float* __restrict__ avgp, const float* __restrict__ maxp,
    const float* __restrict__ w1, const float* __restrict__ b1,
    const float* __restrict__ w2, const float* __restrict__ b2,
    const float* __restrict__ watt, const float* __restrict__ batt,
    unsigned short* __restrict__ Wbf) {
  int blk = blockIdx.x;
  int oc = blk & 255, b = blk >> 8;
  __shared__ float s_avg[25], s_max[25], s_w1[9], s_wgt1[9];
  int tid = threadIdx.x;
  size_t base = ((size_t)b * 256 + oc) * 25;
  if (tid < 25) { s_avg[tid] = avgp[base + tid]; s_max[tid] = maxp[base + tid]; }
  if (tid >= 32 && tid < 41) s_w1[tid - 32] = w1[oc * 9 + (tid - 32)];
  __syncthreads();
  if (tid < 9) {
    int ky = tid / 3, kx = tid % 3;
    float acc = b1[oc];
    for (int u = 0; u < 3; ++u)
      for (int v = 0; v < 3; ++v)
        acc += s_avg[(ky + u) * 5 + kx + v] * s_w1[u * 3 + v];
    s_wgt1[tid] = fmaxf(acc, 0.f);
  }
  __syncthreads();
  int ic = tid;
  size_t g = (size_t)oc * 256 + ic;
  float wa[9];
#pragma unroll
  for (int r = 0; r < 9; ++r) wa[r] = watt[g * 9 + r];
  float ba = batt[g], w2v = w2[g], b2v = b2[g];

  int ocb = oc >> 7, ocl = oc & 127;
  int sa = (ocl >> 1) & 3;
  int icb = ic >> 5, c = (ic >> 3) & 3, sub = ic & 7;
  int cph = c ^ sa;
  size_t tilebase = ((size_t)((b * 2 + ocb) * 8 + icb)) * 9;   // tile units
  size_t elem = (size_t)ocl * 32 + cph * 8 + sub;

#pragma unroll
  for (int r = 0; r < 9; ++r) {
    int ky = r / 3, kx = r % 3;
    float s = ba;
#pragma unroll
    for (int u = 0; u < 3; ++u)
#pragma unroll
      for (int v = 0; v < 3; ++v)
        s += s_max[(ky + u) * 5 + kx + v] * wa[u * 3 + v];
    float att = 1.f / (1.f + __expf(-s));
    float wv = (s_wgt1[r] * w2v + b2v) * att;
    Wbf[(tilebase + r) * 4096 + elem] = f2bf(wv);
  }
}

// ---------------- Kernel 3a: zero the padded border of xp ----------------
__global__ __launch_bounds__(256) void border_kernel(unsigned short* __restrict__ xp) {
  int bid = blockIdx.x;           // 32 * 228
  int b = bid / 228, bi = bid % 228;
  int pos;
  if (bi < 58)       pos = bi;
  else if (bi < 116) pos = 57 * PW + (bi - 58);
  else if (bi < 172) pos = (bi - 116 + 1) * PW;
  else               pos = (bi - 172 + 1) * PW + 57;
  xp[((size_t)b * PAREA + pos) * 256 + threadIdx.x] = 0;
}

// ---------------- Kernel 3b: x fp32 -> xp bf16 [b][pos][ic], PRE-SWIZZLED -------
// within each 32-ic group: logical 8-elem chunk c stored at c ^ ((pos>>1)&3)
__global__ __launch_bounds__(256) void xprep_kernel(const float* __restrict__ x,
                                                    unsigned short* __restrict__ xp) {
  int bid = blockIdx.x;
  int y = bid % 56; int t2 = bid / 56; int icb = t2 & 3; int b = t2 >> 2;
  __shared__ float tr[56][65];
  for (int e = threadIdx.x; e < 56 * 64; e += 256) {
    int icl = e / 56, col = e % 56;
    tr[col][icl] = x[((size_t)(b * 256 + icb * 64 + icl)) * PLANE + y * HW + col];
  }
  __syncthreads();
  for (int e = threadIdx.x; e < 448; e += 256) {
    int col = e >> 3, c8 = e & 7;
    short8 v;
#pragma unroll
    for (int k = 0; k < 8; ++k) v[k] = (short)f2bf(tr[col][c8 * 8 + k]);
    int pos = (y + 1) * PW + (col + 1);
    int sb = (pos >> 1) & 3;
    int c8p = (c8 & 4) | ((c8 & 3) ^ sb);
    size_t dst = ((size_t)b * PAREA + pos) * 256 + icb * 64 + c8p * 8;
    *(short8*)&xp[dst] = v;
  }
}

// ---------------- Kernel 4: dynamic conv via MFMA, pipelined -----------------
// block: 128 oc x (4 rows x 56) px; grid 896 = 8 XCD groups x 112
__global__ __launch_bounds__(256, 2) void conv_kernel(
    const unsigned short* __restrict__ xp,
    const unsigned short* __restrict__ Wbf,
    float* __restrict__ out) {
  __shared__ unsigned short bpl[2][348 * 32];  // 2 x 22272 B, swizzled layout
  __shared__ unsigned short apl[2][128 * 32];  // 2 x  8192 B, swizzled layout

  // XCD swizzle: physical p -> logical L so each XCD owns 4 consecutive batches
  int p = blockIdx.x;
  int L = (p & 7) * 112 + (p >> 3);
  int rt = L % 14; int t2 = L / 14; int ocb = t2 & 1; int b = t2 >> 1;
  int y0 = rt * 4;
  int tid = threadIdx.x;
  int lane = tid & 63, w = tid >> 6;
  int mw = w & 1, nw = w >> 1;     // 2 M-waves x 2 N-waves
  int quad = lane >> 4, l16 = lane & 15;

  int basepos[7];
#pragma unroll
  for (int nt = 0; nt < 7; ++nt) {
    int n = nw * 112 + nt * 16 + l16;
    basepos[nt] = (n / 56) * PW + (n % 56);
  }
  const int sa_off = (quad ^ ((l16 >> 1) & 3)) << 3;  // apl swizzle (elem offset)

  float4v acc[4][7];
#pragma unroll
  for (int mt = 0; mt < 4; ++mt)
#pragma unroll
    for (int nt = 0; nt < 7; ++nt)
      acc[mt][nt] = (float4v){0.f, 0.f, 0.f, 0.f};

  const size_t xbase = ((size_t)b * PAREA + (size_t)y0 * PW) * 256;
  const unsigned short* wb = Wbf + (size_t)((b * 2 + ocb) * 72) * 4096;

  // prologue: stage bpl[0] (icb=0, all 348 pos x 32 ic) + apl[0] (kk=0)
  for (int e = tid; e < 1392; e += 256)
    gll16(&xp[xbase + (size_t)(e >> 2) * 256 + (e & 3) * 8], &bpl[0][e * 8]);
  for (int e = tid; e < 512; e += 256)
    gll16(&wb[e * 8], &apl[0][e * 8]);
  __syncthreads();

  int kk = 0;
  for (int icb = 0; icb < 8; ++icb) {
    for (int r = 0; r < 9; ++r, ++kk) {
      // prefetch next W-slice (contiguous 8KB tile kk+1) into other apl buffer
      if (kk < 71) {
        const unsigned short* asrc = wb + (size_t)(kk + 1) * 4096;
        for (int e = tid; e < 512; e += 256)
          gll16(&asrc[e * 8], &apl[(kk + 1) & 1][e * 8]);
      }
      // prefetch next icb's B-plane, spread over r=0..5
      if (icb < 7 && r < 6) {
        int e = r * 256 + tid;
        if (e < 1392)
          gll16(&xp[xbase + (size_t)(e >> 2) * 256 + (icb + 1) * 32 + (e & 3) * 8],
                &bpl[(icb + 1) & 1][e * 8]);
      }
      int ky = r / 3, kx = r - ky * 3;
      int po = ky * PW + kx;
      short8 bfrag[7];
#pragma unroll
      for (int nt = 0; nt < 7; ++nt) {
        int pr = basepos[nt] + po;
        bfrag[nt] = *(const short8*)&bpl[icb & 1][pr * 32 + ((quad ^ ((pr >> 1) & 3)) << 3)];
      }
#pragma unroll
      for (int mt = 0; mt < 4; ++mt) {
        short8 afrag = *(const short8*)&apl[kk & 1][(mw * 64 + mt * 16 + l16) * 32 + sa_off];
#pragma unroll
        for (int nt = 0; nt < 7; ++nt)
          acc[mt][nt] = __builtin_amdgcn_mfma_f32_16x16x32_bf16(afrag, bfrag[nt], acc[mt][nt], 0, 0, 0);
      }
      __syncthreads();  // drains prefetch vmcnt + protects both double buffers
    }
  }

  // epilogue: D row = quad*4+reg (m), col = l16 (n)
#pragma unroll
  for (int mt = 0; mt < 4; ++mt) {
    int m = ocb * 128 + mw * 64 + mt * 16 + quad * 4;
#pragma unroll
    for (int nt = 0; nt < 7; ++nt) {
      int n = nw * 112 + nt * 16 + l16;
      int yy = y0 + n / 56, xx = n % 56;
      size_t o = (((size_t)b * 256 + m) * 56 + yy) * 56 + xx;
#pragma unroll
      for (int reg = 0; reg < 4; ++reg)
        out[o + (size_t)reg * PLANE] = acc[mt][nt][reg];
    }
  }
}

extern "C" void kernel_launch(void* const* d_in, const int* in_sizes, int n_in,
                              void* d_out, int out_size, void* d_ws, size_t ws_size,
                              hipStream_t stream) {
  const float* x    = (const float*)d_in[0];
  const float* w1   = (const float*)d_in[1];
  const float* b1   = (const float*)d_in[2];
  const float* w2   = (const float*)d_in[3];
  const float* b2   = (const float*)d_in[4];
  const float* watt = (const float*)d_in[5];
  const float* batt = (const float*)d_in[6];
  float* out = (float*)d_out;

  float* avgp = (float*)d_ws;                          // 204800 f32
  float* maxp = avgp + 204800;                         // 204800 f32
  unsigned short* Wbf = (unsigned short*)(maxp + 204800);  // 32*9*256*256 bf16
  unsigned short* xp  = Wbf + (size_t)32 * 9 * 256 * 256;  // 32*3364*256 bf16

  pool_kernel<<<BATCH * CIN, 256, 0, stream>>>(x, avgp, maxp);
  wcalc_kernel<<<BATCH * OCH, 256, 0, stream>>>(avgp, maxp, w1, b1, w2, b2, watt, batt, Wbf);
  border_kernel<<<BATCH * 228, 256, 0, stream>>>(xp);
  xprep_kernel<<<BATCH * 4 * 56, 256, 0, stream>>>(x, xp);
  conv_kernel<<<BATCH * 2 * 14, 256, 0, stream>>>(xp, Wbf, out);
}

// Round 3
// 475.162 us; speedup vs baseline: 1.3931x; 1.3931x over previous
//
#include <hip/hip_runtime.h>
#include <hip/hip_bf16.h>

#define BATCH 32
#define CIN   256
#define OCH   256
#define HW    56
#define PW    58
#define PAREA (PW*PW)   /* 3364 */
#define PLANE (HW*HW)   /* 3136 */

typedef float float4v __attribute__((ext_vector_type(4)));
typedef short short8  __attribute__((ext_vector_type(8)));

__device__ __forceinline__ unsigned short f2bf(float f) {
  union { float f; unsigned u; } v; v.f = f;
  unsigned r = v.u + 0x7fffu + ((v.u >> 16) & 1u);
  return (unsigned short)(r >> 16);
}

// async global->LDS, 16B per lane, LDS dest linear in lane order
__device__ __forceinline__ void gll16(const unsigned short* g, unsigned short* l) {
  __builtin_amdgcn_global_load_lds(
      (const __attribute__((address_space(1))) void*)g,
      (__attribute__((address_space(3))) void*)l,
      16, 0, 0);
}

// ---------------- Kernel 1: fused pool (avg+max 56x56->5x5) + xp prep -----------
// block = (b, group of 8 channels); reads x ONCE, writes pools + swizzled xp.
__global__ __launch_bounds__(1024) void poolprep_kernel(
    const float* __restrict__ x, float* __restrict__ avgp,
    float* __restrict__ maxp, unsigned short* __restrict__ xp) {
  __shared__ float pl[8][3140];   // 3140 pad: stride%32==4 -> conflict-free phases
  int bid = blockIdx.x;
  int cg = bid & 31, b = bid >> 5;     // channels cg*8 .. cg*8+7
  int tid = threadIdx.x;
  const float* src = x + ((size_t)(b * 256 + cg * 8)) * PLANE;

  // load 8 planes (6272 float4), 7-deep in flight per thread
  float4v v[7];
#pragma unroll
  for (int k = 0; k < 7; ++k) {
    int e = tid + k * 1024;
    if (e < 6272) v[k] = *(const float4v*)&src[(size_t)(e / 784) * PLANE + (e % 784) * 4];
  }
#pragma unroll
  for (int k = 0; k < 7; ++k) {
    int e = tid + k * 1024;
    if (e < 6272) *(float4v*)&pl[e / 784][(e % 784) * 4] = v[k];
  }
  __syncthreads();

  // pool: 8 channels x 25 bins, bit-identical loop to original
  if (tid < 200) {
    int c = tid / 25, bin = tid % 25;
    int i = bin / 5, j = bin % 5;
    int r0 = (i * HW) / 5, r1 = ((i + 1) * HW + 4) / 5;
    int c0 = (j * HW) / 5, c1 = ((j + 1) * HW + 4) / 5;
    float s = 0.f, m = -1e30f;
    for (int r = r0; r < r1; ++r)
      for (int c2 = c0; c2 < c1; ++c2) {
        float vv = pl[c][r * HW + c2];
        s += vv; m = fmaxf(m, vv);
      }
    size_t o = ((size_t)(b * 256 + cg * 8 + c)) * 25 + bin;
    avgp[o] = s / (float)((r1 - r0) * (c1 - c0));
    maxp[o] = m;
  }

  // xp: bf16 chunks [b][pos][ic], swizzled: chunk c stored at c ^ ((pos>>1)&3)
  int g32 = cg >> 2, cc = cg & 3;
  for (int p = tid; p < PLANE; p += 1024) {
    int y = p / 56, col = p % 56;
    int pos = (y + 1) * PW + (col + 1);
    short8 w8;
#pragma unroll
    for (int k = 0; k < 8; ++k) w8[k] = (short)f2bf(pl[k][p]);
    int cph = cc ^ ((pos >> 1) & 3);
    *(short8*)&xp[((size_t)b * PAREA + pos) * 256 + g32 * 32 + cph * 8] = w8;
  }
}

// ---------------- Kernel 2: dynamic weight computation ----------------
// Wbf layout: tiles [b][ocb2][icb8][r9] of [oc 128][ic 32] (UNswizzled, 8KB/tile)
__global__ __launch_bounds__(256) void wcalc_kernel(
    const float* __restrict__ avgp, const float* __restrict__ maxp,
    const float* __restrict__ w1, const float* __restrict__ b1,
    const float* __restrict__ w2, const float* __restrict__ b2,
    const float* __restrict__ watt, const float* __restrict__ batt,
    unsigned short* __restrict__ Wbf) {
  int blk = blockIdx.x;
  int oc = blk & 255, b = blk >> 8;
  __shared__ float s_avg[25], s_max[25], s_w1[9], s_wgt1[9];
  int tid = threadIdx.x;
  size_t base = ((size_t)b * 256 + oc) * 25;
  if (tid < 25) { s_avg[tid] = avgp[base + tid]; s_max[tid] = maxp[base + tid]; }
  if (tid >= 32 && tid < 41) s_w1[tid - 32] = w1[oc * 9 + (tid - 32)];
  __syncthreads();
  if (tid < 9) {
    int ky = tid / 3, kx = tid % 3;
    float acc = b1[oc];
    for (int u = 0; u < 3; ++u)
      for (int v = 0; v < 3; ++v)
        acc += s_avg[(ky + u) * 5 + kx + v] * s_w1[u * 3 + v];
    s_wgt1[tid] = fmaxf(acc, 0.f);
  }
  __syncthreads();
  int ic = tid;
  size_t g = (size_t)oc * 256 + ic;
  float wa[9];
#pragma unroll
  for (int r = 0; r < 9; ++r) wa[r] = watt[g * 9 + r];
  float ba = batt[g], w2v = w2[g], b2v = b2[g];

  int ocb = oc >> 7, ocl = oc & 127;
  int icb = ic >> 5;
  size_t tilebase = ((size_t)((b * 2 + ocb) * 8 + icb)) * 9;   // tile units
  size_t elem = (size_t)ocl * 32 + (ic & 31);

#pragma unroll
  for (int r = 0; r < 9; ++r) {
    int ky = r / 3, kx = r % 3;
    float s = ba;
#pragma unroll
    for (int u = 0; u < 3; ++u)
#pragma unroll
      for (int v = 0; v < 3; ++v)
        s += s_max[(ky + u) * 5 + kx + v] * wa[u * 3 + v];
    float att = 1.f / (1.f + __expf(-s));
    float wv = (s_wgt1[r] * w2v + b2v) * att;
    Wbf[(tilebase + r) * 4096 + elem] = f2bf(wv);
  }
}

// ---------------- Kernel 3a: zero the padded border of xp ----------------
__global__ __launch_bounds__(256) void border_kernel(unsigned short* __restrict__ xp) {
  int bid = blockIdx.x;           // 32 * 228
  int b = bid / 228, bi = bid % 228;
  int pos;
  if (bi < 58)       pos = bi;
  else if (bi < 116) pos = 57 * PW + (bi - 58);
  else if (bi < 172) pos = (bi - 116 + 1) * PW;
  else               pos = (bi - 172 + 1) * PW + 57;
  xp[((size_t)b * PAREA + pos) * 256 + threadIdx.x] = 0;
}

// ---------------- Kernel 4: dynamic conv via MFMA ------------------------------
// A (weights) straight from global to registers (coalesced 1KB/wave, L2-resident)
// B (pixels) LDS double-buffered via global_load_lds; ONE barrier per icb.
__global__ __launch_bounds__(256, 2) void conv_kernel(
    const unsigned short* __restrict__ xp,
    const unsigned short* __restrict__ Wbf,
    float* __restrict__ out) {
  __shared__ unsigned short bpl[2][348 * 32];  // 2 x 22272 B, swizzled layout

  // XCD swizzle: each XCD gets 4 consecutive batches (blocks sharing Wbf/xp)
  int p = blockIdx.x;
  int L = (p & 7) * 112 + (p >> 3);
  int rt = L % 14; int t2 = L / 14; int ocb = t2 & 1; int b = t2 >> 1;
  int y0 = rt * 4;
  int tid = threadIdx.x;
  int lane = tid & 63, w = tid >> 6;
  int mw = w & 1, nw = w >> 1;     // 2 M-waves x 2 N-waves
  int quad = lane >> 4, l16 = lane & 15;

  int basepos[7];
#pragma unroll
  for (int nt = 0; nt < 7; ++nt) {
    int n = nw * 112 + nt * 16 + l16;
    basepos[nt] = (n / 56) * PW + (n % 56);
  }

  float4v acc[4][7];
#pragma unroll
  for (int mt = 0; mt < 4; ++mt)
#pragma unroll
    for (int nt = 0; nt < 7; ++nt)
      acc[mt][nt] = (float4v){0.f, 0.f, 0.f, 0.f};

  const size_t xbase = ((size_t)b * PAREA + (size_t)y0 * PW) * 256;
  const unsigned short* wb = Wbf + (size_t)((b * 2 + ocb) * 72) * 4096;
  const int aoff = (mw * 64 + l16) * 32 + quad * 8;   // + mt*512 per m-tile

  // prologue: stage bpl[0] (icb=0)
  for (int e = tid; e < 1392; e += 256)
    gll16(&xp[xbase + (size_t)(e >> 2) * 256 + (e & 3) * 8], &bpl[0][e * 8]);
  __syncthreads();

  for (int icb = 0; icb < 8; ++icb) {
    int cur = icb & 1;
    // async prefetch next icb's B-plane into the other buffer
    if (icb < 7) {
      for (int e = tid; e < 1392; e += 256)
        gll16(&xp[xbase + (size_t)(e >> 2) * 256 + (icb + 1) * 32 + (e & 3) * 8],
              &bpl[cur ^ 1][e * 8]);
    }
    const unsigned short* wt = wb + (size_t)icb * 9 * 4096;
#pragma unroll
    for (int r = 0; r < 9; ++r) {
      short8 af[4];
#pragma unroll
      for (int mt = 0; mt < 4; ++mt)
        af[mt] = *(const short8*)&wt[(size_t)r * 4096 + mt * 512 + aoff];
      int ky = r / 3, kx = r - ky * 3;
      int po = ky * PW + kx;
      short8 bfrag[7];
#pragma unroll
      for (int nt = 0; nt < 7; ++nt) {
        int pr = basepos[nt] + po;
        bfrag[nt] = *(const short8*)&bpl[cur][pr * 32 + ((quad ^ ((pr >> 1) & 3)) << 3)];
      }
#pragma unroll
      for (int mt = 0; mt < 4; ++mt)
#pragma unroll
        for (int nt = 0; nt < 7; ++nt)
          acc[mt][nt] = __builtin_amdgcn_mfma_f32_16x16x32_bf16(af[mt], bfrag[nt], acc[mt][nt], 0, 0, 0);
    }
    __syncthreads();  // drains prefetch (vmcnt 0) + protects double buffer; 8x/block
  }

  // epilogue: D row = quad*4+reg (m), col = l16 (n)
#pragma unroll
  for (int mt = 0; mt < 4; ++mt) {
    int m = ocb * 128 + mw * 64 + mt * 16 + quad * 4;
#pragma unroll
    for (int nt = 0; nt < 7; ++nt) {
      int n = nw * 112 + nt * 16 + l16;
      int yy = y0 + n / 56, xx = n % 56;
      size_t o = (((size_t)b * 256 + m) * 56 + yy) * 56 + xx;
#pragma unroll
      for (int reg = 0; reg < 4; ++reg)
        out[o + (size_t)reg * PLANE] = acc[mt][nt][reg];
    }
  }
}

extern "C" void kernel_launch(void* const* d_in, const int* in_sizes, int n_in,
                              void* d_out, int out_size, void* d_ws, size_t ws_size,
                              hipStream_t stream) {
  const float* x    = (const float*)d_in[0];
  const float* w1   = (const float*)d_in[1];
  const float* b1   = (const float*)d_in[2];
  const float* w2   = (const float*)d_in[3];
  const float* b2   = (const float*)d_in[4];
  const float* watt = (const float*)d_in[5];
  const float* batt = (const float*)d_in[6];
  float* out = (float*)d_out;

  float* avgp = (float*)d_ws;                          // 204800 f32
  float* maxp = avgp + 204800;                         // 204800 f32
  unsigned short* Wbf = (unsigned short*)(maxp + 204800);  // 32*9*256*256 bf16
  unsigned short* xp  = Wbf + (size_t)32 * 9 * 256 * 256;  // 32*3364*256 bf16

  poolprep_kernel<<<BATCH * 32, 1024, 0, stream>>>(x, avgp, maxp, xp);
  wcalc_kernel<<<BATCH * OCH, 256, 0, stream>>>(avgp, maxp, w1, b1, w2, b2, watt, batt, Wbf);
  border_kernel<<<BATCH * 228, 256, 0, stream>>>(xp);
  conv_kernel<<<BATCH * 2 * 14, 256, 0, stream>>>(xp, Wbf, out);
}